// Round 1
// baseline (489.792 us; speedup 1.0000x reference)
//
#include <hip/hip_runtime.h>

#define E_EXT 128
#define S_SEG 64
#define P_PATH 256
#define SE 8192  // S_SEG * E_EXT

// ws layout:
//   [0, 260)          : int seg_start[S_SEG+1]
//   [1024, 1024+4096) : int4 meta[P_PATH]  {i1*64, i2*64, coeff_bits, i3}

__global__ __launch_bounds__(P_PATH) void build_paths_kernel(
    const float* __restrict__ coeff,
    const int* __restrict__ pidx,
    int* __restrict__ seg_start,
    int4* __restrict__ meta)
{
    __shared__ int i3s[P_PATH];
    __shared__ int cnt[S_SEG];
    __shared__ int base[S_SEG + 1];
    const int t = threadIdx.x;
    const int i1 = pidx[3 * t + 0];
    const int i2 = pidx[3 * t + 1];
    const int i3 = pidx[3 * t + 2];
    i3s[t] = i3;
    __syncthreads();
    // deterministic rank of path t within its segment
    int pos = 0;
    for (int q = 0; q < t; ++q) pos += (i3s[q] == i3) ? 1 : 0;
    if (t < S_SEG) {
        int c = 0;
        for (int q = 0; q < P_PATH; ++q) c += (i3s[q] == t) ? 1 : 0;
        cnt[t] = c;
    }
    __syncthreads();
    if (t == 0) {
        int run = 0;
        for (int s = 0; s < S_SEG; ++s) { base[s] = run; run += cnt[s]; }
        base[S_SEG] = run;
    }
    __syncthreads();
    if (t <= S_SEG) seg_start[t] = base[t];
    // offsets pre-scaled to float2 units (E/2 = 64)
    meta[base[i3] + pos] = make_int4(i1 * (E_EXT / 2), i2 * (E_EXT / 2),
                                     __float_as_int(coeff[t]), i3);
}

__global__ __launch_bounds__(512) void tp_main_kernel(
    const float* __restrict__ x_table,
    const float* __restrict__ y,
    const int* __restrict__ x_idx,
    const int* __restrict__ seg_start,
    const int4* __restrict__ meta,
    float* __restrict__ out)
{
    __shared__ float xs[SE];
    __shared__ float ys[SE];
    const int b = blockIdx.x;
    const int t = threadIdx.x;

    // Stage x row (gathered) and y row into LDS: 32 KB each, coalesced float4.
    const float4* __restrict__ xsrc =
        (const float4*)(x_table + (size_t)x_idx[b] * SE);
    const float4* __restrict__ ysrc = (const float4*)(y + (size_t)b * SE);
    float4* xd = (float4*)xs;
    float4* yd = (float4*)ys;
#pragma unroll
    for (int i = 0; i < SE / 4 / 512; ++i) {  // 4 iterations
        xd[t + i * 512] = xsrc[t + i * 512];
        yd[t + i * 512] = ysrc[t + i * 512];
    }
    __syncthreads();

    const int w = t >> 6;   // wave 0..7 -> owns segments [8w, 8w+8)
    const int l = t & 63;   // lane      -> owns e = 2l, 2l+1
    const float2* __restrict__ xs2 = (const float2*)xs;
    const float2* __restrict__ ys2 = (const float2*)ys;
    float* __restrict__ orow = out + (size_t)b * SE;

#pragma unroll
    for (int si = 0; si < 8; ++si) {
        const int s3 = w * 8 + si;
        // wave-uniform loads -> scalar path
        const int js = seg_start[s3];
        const int je = seg_start[s3 + 1];
        float a0 = 0.f, a1 = 0.f;
        for (int j = js; j < je; ++j) {
            const int4 r = meta[j];  // wave-uniform address
            const float c = __int_as_float(r.z);
            const float2 xv = xs2[r.x + l];
            const float2 yv = ys2[r.y + l];
            a0 = fmaf(c * xv.x, yv.x, a0);
            a1 = fmaf(c * xv.y, yv.y, a1);
        }
        ((float2*)(orow + (size_t)s3 * E_EXT))[l] = make_float2(a0, a1);
    }
}

extern "C" void kernel_launch(void* const* d_in, const int* in_sizes, int n_in,
                              void* d_out, int out_size, void* d_ws, size_t ws_size,
                              hipStream_t stream) {
    const float* x_table   = (const float*)d_in[0];
    const float* y         = (const float*)d_in[1];
    const float* path_coef = (const float*)d_in[2];
    const int*   x_idx     = (const int*)d_in[3];
    const int*   path_idx  = (const int*)d_in[4];
    float* out = (float*)d_out;

    int* seg_start = (int*)d_ws;
    int4* meta = (int4*)((char*)d_ws + 1024);

    const int B = in_sizes[3];  // 4096 (x_idx count)

    build_paths_kernel<<<1, P_PATH, 0, stream>>>(path_coef, path_idx, seg_start, meta);
    tp_main_kernel<<<B, 512, 0, stream>>>(x_table, y, x_idx, seg_start, meta, out);
}

// Round 2
// 464.201 us; speedup vs baseline: 1.0551x; 1.0551x over previous
//
#include <hip/hip_runtime.h>

#define E_EXT 128
#define S_SEG 64
#define P_PATH 256
#define SE 8192  // S_SEG * E_EXT

// ws layout:
//   [0, 260)          : int seg_start[S_SEG+1]
//   [1024, 1024+4096) : int4 meta[P_PATH]  {i1*64, i2*64, coeff_bits, i3}

__global__ __launch_bounds__(P_PATH) void build_paths_kernel(
    const float* __restrict__ coeff,
    const int* __restrict__ pidx,
    int* __restrict__ seg_start,
    int4* __restrict__ meta)
{
    __shared__ int i3s[P_PATH];
    __shared__ int cnt[S_SEG];
    __shared__ int base[S_SEG + 1];
    const int t = threadIdx.x;
    const int i1 = pidx[3 * t + 0];
    const int i2 = pidx[3 * t + 1];
    const int i3 = pidx[3 * t + 2];
    i3s[t] = i3;
    __syncthreads();
    // deterministic rank of path t within its segment
    int pos = 0;
    for (int q = 0; q < t; ++q) pos += (i3s[q] == i3) ? 1 : 0;
    if (t < S_SEG) {
        int c = 0;
        for (int q = 0; q < P_PATH; ++q) c += (i3s[q] == t) ? 1 : 0;
        cnt[t] = c;
    }
    __syncthreads();
    if (t == 0) {
        int run = 0;
        for (int s = 0; s < S_SEG; ++s) { base[s] = run; run += cnt[s]; }
        base[S_SEG] = run;
    }
    __syncthreads();
    if (t <= S_SEG) seg_start[t] = base[t];
    // offsets pre-scaled to float2 units (E/2 = 64)
    meta[base[i3] + pos] = make_int4(i1 * (E_EXT / 2), i2 * (E_EXT / 2),
                                     __float_as_int(coeff[t]), i3);
}

__global__ __launch_bounds__(512, 2) void tp_main_kernel(
    const float* __restrict__ x_table,
    const float* __restrict__ y,
    const int* __restrict__ x_idx,
    const int* __restrict__ seg_start,
    const int4* __restrict__ meta,
    float* __restrict__ out)
{
    __shared__ float xs[SE];
    __shared__ float ys[SE];
    __shared__ int4 smeta[P_PATH];
    __shared__ int sstart[S_SEG + 1];
    const int b = blockIdx.x;
    const int t = threadIdx.x;

    // Stage x row (gathered) and y row into LDS: 32 KB each, coalesced float4.
    // Also stage path metadata (4 KB) + segment offsets so the inner loop
    // never touches global memory.
    const float4* __restrict__ xsrc =
        (const float4*)(x_table + (size_t)x_idx[b] * SE);
    const float4* __restrict__ ysrc = (const float4*)(y + (size_t)b * SE);
    float4* xd = (float4*)xs;
    float4* yd = (float4*)ys;
#pragma unroll
    for (int i = 0; i < SE / 4 / 512; ++i) {  // 4 iterations
        xd[t + i * 512] = xsrc[t + i * 512];
        yd[t + i * 512] = ysrc[t + i * 512];
    }
    if (t < P_PATH) smeta[t] = meta[t];
    if (t <= S_SEG) sstart[t] = seg_start[t];
    __syncthreads();

    const int w = t >> 6;   // wave 0..7 -> owns segments [8w, 8w+8)
    const int l = t & 63;   // lane      -> owns e = 2l, 2l+1
    const float2* __restrict__ xs2 = (const float2*)xs;
    const float2* __restrict__ ys2 = (const float2*)ys;
    float* __restrict__ orow = out + (size_t)b * SE;

#pragma unroll
    for (int si = 0; si < 8; ++si) {
        const int s3 = w * 8 + si;
        const int js = sstart[s3];       // LDS broadcast
        const int je = sstart[s3 + 1];
        float a0 = 0.f, a1 = 0.f;
        int4 r;
        if (js < je) r = smeta[js];      // prime the pipeline
        for (int j = js; j < je; ++j) {
            const int4 cur = r;
            if (j + 1 < je) r = smeta[j + 1];  // prefetch next meta (LDS broadcast)
            const float c = __int_as_float(cur.z);
            const float2 xv = xs2[cur.x + l];
            const float2 yv = ys2[cur.y + l];
            a0 = fmaf(c * xv.x, yv.x, a0);
            a1 = fmaf(c * xv.y, yv.y, a1);
        }
        ((float2*)(orow + (size_t)s3 * E_EXT))[l] = make_float2(a0, a1);
    }
}

extern "C" void kernel_launch(void* const* d_in, const int* in_sizes, int n_in,
                              void* d_out, int out_size, void* d_ws, size_t ws_size,
                              hipStream_t stream) {
    const float* x_table   = (const float*)d_in[0];
    const float* y         = (const float*)d_in[1];
    const float* path_coef = (const float*)d_in[2];
    const int*   x_idx     = (const int*)d_in[3];
    const int*   path_idx  = (const int*)d_in[4];
    float* out = (float*)d_out;

    int* seg_start = (int*)d_ws;
    int4* meta = (int4*)((char*)d_ws + 1024);

    const int B = in_sizes[3];  // 4096 (x_idx count)

    build_paths_kernel<<<1, P_PATH, 0, stream>>>(path_coef, path_idx, seg_start, meta);
    tp_main_kernel<<<B, 512, 0, stream>>>(x_table, y, x_idx, seg_start, meta, out);
}